// Round 4
// baseline (211.132 us; speedup 1.0000x reference)
//
#include <hip/hip_runtime.h>
#include <math.h>

typedef __attribute__((ext_vector_type(4))) float f32x4;
typedef __attribute__((ext_vector_type(4))) _Float16 f16x4;

#define B_  16
#define D_  2048
#define H_  16
#define HD_ 128
#define LP_ 2048
#define M_  8192
#define QKV_R (3 * D_)
#define SCALE 0.08838834764831845f   // 1/sqrt(128)
#define NSPLIT 64
#define KPS 32   // keys per split (LP_ / NSPLIT)

__device__ inline float wave_sum(float v) {
  for (int m = 32; m > 0; m >>= 1) v += __shfl_xor(v, m);
  return v;
}

// ---------------- LayerNorm: one block per batch row, 256 threads ----------
__global__ void ln_kernel(const float* __restrict__ x, const float* __restrict__ w,
                          const float* __restrict__ bb, float* __restrict__ o) {
  __shared__ float sred[4];
  int b = blockIdx.x, t = threadIdx.x;
  const float* xr = x + (size_t)b * D_;
  f32x4 v0 = *(const f32x4*)(xr + t * 8);
  f32x4 v1 = *(const f32x4*)(xr + t * 8 + 4);
  float s = (v0[0] + v0[1] + v0[2] + v0[3]) + (v1[0] + v1[1] + v1[2] + v1[3]);
  s = wave_sum(s);
  if ((t & 63) == 0) sred[t >> 6] = s;
  __syncthreads();
  float mu = (sred[0] + sred[1] + sred[2] + sred[3]) * (1.0f / D_);
  __syncthreads();
  float sq = 0.f;
  for (int i = 0; i < 4; i++) {
    float d0 = v0[i] - mu; sq += d0 * d0;
    float d1 = v1[i] - mu; sq += d1 * d1;
  }
  sq = wave_sum(sq);
  if ((t & 63) == 0) sred[t >> 6] = sq;
  __syncthreads();
  float var = (sred[0] + sred[1] + sred[2] + sred[3]) * (1.0f / D_);
  float rs = rsqrtf(var + 1e-5f);
  f32x4 w0 = *(const f32x4*)(w + t * 8), w1 = *(const f32x4*)(w + t * 8 + 4);
  f32x4 c0 = *(const f32x4*)(bb + t * 8), c1 = *(const f32x4*)(bb + t * 8 + 4);
  f32x4 o0, o1;
  for (int i = 0; i < 4; i++) {
    o0[i] = (v0[i] - mu) * rs * w0[i] + c0[i];
    o1[i] = (v1[i] - mu) * rs * w1[i] + c1[i];
  }
  *(f32x4*)(o + (size_t)b * D_ + t * 8) = o0;
  *(f32x4*)(o + (size_t)b * D_ + t * 8 + 4) = o1;
}

// ---------------- Skinny GEMM: C[16,R] = X[16,K] @ W[R,K]^T ----------------
__global__ void gemv_k(const float* __restrict__ W, const float* __restrict__ X,
                       float* __restrict__ part, int R, int K, int kc) {
  int wave = threadIdx.x >> 6, lane = threadIdx.x & 63;
  int j0 = (blockIdx.x * 4 + wave) * 16;
  int k0 = blockIdx.y * kc;
  int col = lane & 15;
  int kg  = (lane >> 4) << 2;
  const float* wp = W + (size_t)(j0 + col) * K + k0 + kg;
  const float* xp = X + (size_t)col * K + k0 + kg;
  f32x4 acc = {0.f, 0.f, 0.f, 0.f};
  #pragma unroll 4
  for (int kk = 0; kk < kc; kk += 16) {
    f32x4 av = *(const f32x4*)xp; xp += 16;
    f32x4 bv = *(const f32x4*)wp; wp += 16;
    f16x4 ah, bh;
    for (int i = 0; i < 4; i++) { ah[i] = (_Float16)av[i]; bh[i] = (_Float16)bv[i]; }
    acc = __builtin_amdgcn_mfma_f32_16x16x16f16(ah, bh, acc, 0, 0, 0);
  }
  *(f32x4*)(part + ((size_t)blockIdx.y * R + j0 + col) * 16 + kg) = acc;
}

// ---------------- split-K reduce + epilogues -------------------------------
__global__ void reduce_plain(const float* __restrict__ part, float* __restrict__ out,
                             int R, int S) {
  int i = blockIdx.x * 256 + threadIdx.x;
  int j = i >> 4, b = i & 15;
  float s = 0.f;
  for (int k = 0; k < S; k++) s += part[(size_t)k * R * 16 + i];
  out[(size_t)b * R + j] = s;
}
__global__ void reduce_resid(const float* __restrict__ part, const float* __restrict__ resid,
                             float* __restrict__ out, int R, int S) {
  int i = blockIdx.x * 256 + threadIdx.x;
  int j = i >> 4, b = i & 15;
  float s = 0.f;
  for (int k = 0; k < S; k++) s += part[(size_t)k * R * 16 + i];
  out[(size_t)b * R + j] = resid[(size_t)b * R + j] + s;
}
__global__ void reduce_bias_gelu(const float* __restrict__ part, const float* __restrict__ bias,
                                 float* __restrict__ out, int R, int S) {
  int i = blockIdx.x * 256 + threadIdx.x;
  int j = i >> 4, b = i & 15;
  float s = 0.f;
  for (int k = 0; k < S; k++) s += part[(size_t)k * R * 16 + i];
  float u = s + bias[j];
  out[(size_t)b * R + j] = 0.5f * u * (1.0f + erff(u * 0.70710678118654752f));
}
__global__ void reduce_bias_resid(const float* __restrict__ part, const float* __restrict__ bias,
                                  const float* __restrict__ resid, float* __restrict__ out,
                                  int R, int S) {
  int i = blockIdx.x * 256 + threadIdx.x;
  int j = i >> 4, b = i & 15;
  float s = 0.f;
  for (int k = 0; k < S; k++) s += part[(size_t)k * R * 16 + i];
  out[(size_t)b * R + j] = resid[(size_t)b * R + j] + s + bias[j];
}

// ---------------- attention pass 1: scores (pure K stream) -----------------
// grid (B, NSPLIT), 256 threads. Thread t: head h=t>>4, dims (t&15)*8..+8.
// Single read stream, trivial consumption (8 FMA + 4 shfl per 32 B).
// Scores written [b][h][l] (l contiguous) via LDS transpose, coalesced.
__global__ void attn_scores(const float* __restrict__ qkv, const float* __restrict__ pk,
                            float* __restrict__ scores) {
  int b = blockIdx.x, split = blockIdx.y;
  int t = threadIdx.x;
  int h = t >> 4;
  __shared__ float s_t[KPS][17];
  f32x4 q0 = *(const f32x4*)(qkv + (size_t)b * QKV_R + t * 8);
  f32x4 q1 = *(const f32x4*)(qkv + (size_t)b * QKV_R + t * 8 + 4);
  for (int i = 0; i < 4; i++) { q0[i] *= SCALE; q1[i] *= SCALE; }
  const float* kb = pk + ((size_t)b * LP_ + (size_t)split * KPS) * D_ + t * 8;
  for (int l0 = 0; l0 < KPS; l0 += 8) {
    f32x4 k0[8], k1[8];
    #pragma unroll
    for (int c = 0; c < 8; c++) {
      size_t off = (size_t)(l0 + c) * D_;
      k0[c] = *(const f32x4*)(kb + off);
      k1[c] = *(const f32x4*)(kb + off + 4);
    }
    #pragma unroll
    for (int c = 0; c < 8; c++) {
      float s = q0[0]*k0[c][0] + q0[1]*k0[c][1] + q0[2]*k0[c][2] + q0[3]*k0[c][3]
              + q1[0]*k1[c][0] + q1[1]*k1[c][1] + q1[2]*k1[c][2] + q1[3]*k1[c][3];
      s += __shfl_xor(s, 1); s += __shfl_xor(s, 2);
      s += __shfl_xor(s, 4); s += __shfl_xor(s, 8);
      if ((t & 15) == 0) s_t[l0 + c][h] = s;
    }
  }
  __syncthreads();
  if ((t & 15) < 8) {
    int l4 = (t & 15) * 4;
    f32x4 o;
    for (int i = 0; i < 4; i++) o[i] = s_t[l4 + i][h];
    *(f32x4*)(scores + (size_t)(b * H_ + h) * LP_ + (size_t)split * KPS + l4) = o;
  }
}

// ---------------- attention pass 2: softmax over 2048+1 -------------------
// grid 256 = (b,h), 256 threads. Normalized probs written in place; the new
// token's prob goes to pml[bh].
__global__ void attn_soft(const float* __restrict__ qkv, float* __restrict__ scores,
                          float* __restrict__ pml) {
  int bh = blockIdx.x, b = bh >> 4, h = bh & 15;
  int t = threadIdx.x;
  __shared__ float sred[4];
  float prod = 0.f;
  if (t < 128) {
    float qv = qkv[(size_t)b * QKV_R + h * HD_ + t];
    float kn = qkv[(size_t)b * QKV_R + D_ + h * HD_ + t];
    prod = qv * kn;
  }
  prod = wave_sum(prod);
  if ((t & 63) == 0) sred[t >> 6] = prod;
  __syncthreads();
  float s_new = (sred[0] + sred[1] + sred[2] + sred[3]) * SCALE;
  __syncthreads();
  float* sp = scores + (size_t)bh * LP_;
  f32x4 v0 = *(const f32x4*)(sp + t * 8);
  f32x4 v1 = *(const f32x4*)(sp + t * 8 + 4);
  float m = s_new;
  for (int i = 0; i < 4; i++) m = fmaxf(m, fmaxf(v0[i], v1[i]));
  for (int mm = 32; mm > 0; mm >>= 1) m = fmaxf(m, __shfl_xor(m, mm));
  if ((t & 63) == 0) sred[t >> 6] = m;
  __syncthreads();
  float M = fmaxf(fmaxf(sred[0], sred[1]), fmaxf(sred[2], sred[3]));
  __syncthreads();
  float ls = 0.f;
  for (int i = 0; i < 4; i++) {
    v0[i] = __expf(v0[i] - M); ls += v0[i];
    v1[i] = __expf(v1[i] - M); ls += v1[i];
  }
  ls = wave_sum(ls);
  if ((t & 63) == 0) sred[t >> 6] = ls;
  __syncthreads();
  float en = __expf(s_new - M);
  float L = sred[0] + sred[1] + sred[2] + sred[3] + en;
  float inv = 1.0f / L;
  for (int i = 0; i < 4; i++) { v0[i] *= inv; v1[i] *= inv; }
  *(f32x4*)(sp + t * 8) = v0;
  *(f32x4*)(sp + t * 8 + 4) = v1;
  if (t == 0) pml[bh] = en * inv;
}

// ---------------- attention pass 3: A@V (pure V stream) --------------------
// grid (B, NSPLIT), 256 threads. Probs are final (normalized): plain partial
// sums, broadcast f32x4 prob loads (same addr across the 16-lane group).
__global__ void attn_av(const float* __restrict__ scores, const float* __restrict__ pv,
                        float* __restrict__ pacc) {
  int b = blockIdx.x, split = blockIdx.y;
  int t = threadIdx.x, h = t >> 4;
  const float* vb = pv + ((size_t)b * LP_ + (size_t)split * KPS) * D_ + t * 8;
  const float* pp = scores + (size_t)(b * H_ + h) * LP_ + (size_t)split * KPS;
  f32x4 a0 = {0.f, 0.f, 0.f, 0.f}, a1 = {0.f, 0.f, 0.f, 0.f};
  for (int l0 = 0; l0 < KPS; l0 += 8) {
    f32x4 p0 = *(const f32x4*)(pp + l0);
    f32x4 p1 = *(const f32x4*)(pp + l0 + 4);
    f32x4 w0[8], w1[8];
    #pragma unroll
    for (int c = 0; c < 8; c++) {
      size_t off = (size_t)(l0 + c) * D_;
      w0[c] = *(const f32x4*)(vb + off);
      w1[c] = *(const f32x4*)(vb + off + 4);
    }
    #pragma unroll
    for (int c = 0; c < 8; c++) {
      float p = (c < 4) ? p0[c] : p1[c - 4];
      for (int i = 0; i < 4; i++) { a0[i] += p * w0[c][i]; a1[i] += p * w1[c][i]; }
    }
  }
  size_t oi = (((size_t)b * NSPLIT + split) * H_ + h) * HD_ + (t & 15) * 8;
  *(f32x4*)(pacc + oi) = a0;
  *(f32x4*)(pacc + oi + 4) = a1;
}

// ---------------- combine partials + new token -----------------------------
__global__ void attn_comb(const float* __restrict__ qkv, const float* __restrict__ pml,
                          const float* __restrict__ pacc, float* __restrict__ attn_out) {
  int bh = blockIdx.x, b = bh >> 4, h = bh & 15;
  int t = threadIdx.x;  // 128
  float o = 0.f;
  for (int s = 0; s < NSPLIT; s++)
    o += pacc[(((size_t)b * NSPLIT + s) * H_ + h) * HD_ + t];
  o += pml[bh] * qkv[(size_t)b * QKV_R + 2 * D_ + h * HD_ + t];
  attn_out[(size_t)b * D_ + h * HD_ + t] = o;
}

extern "C" void kernel_launch(void* const* d_in, const int* in_sizes, int n_in,
                              void* d_out, int out_size, void* d_ws, size_t ws_size,
                              hipStream_t stream) {
  const float* input  = (const float*)d_in[0];
  const float* pk     = (const float*)d_in[1];
  const float* pv     = (const float*)d_in[2];
  const float* ln0_w  = (const float*)d_in[3];
  const float* ln0_b  = (const float*)d_in[4];
  const float* ln1_w  = (const float*)d_in[5];
  const float* ln1_b  = (const float*)d_in[6];
  const float* wqkv   = (const float*)d_in[7];
  const float* wo     = (const float*)d_in[8];
  const float* fc0_w  = (const float*)d_in[9];
  const float* fc0_b  = (const float*)d_in[10];
  const float* fc1_w  = (const float*)d_in[11];
  const float* fc1_b  = (const float*)d_in[12];
  float* out = (float*)d_out;

  char* wsb = (char*)d_ws;
  float* x_ln     = (float*)(wsb + 0);         // 16x2048           128 KB
  float* qkv      = (float*)(wsb + 131072);    // 16x6144           384 KB
  float* attn_out = (float*)(wsb + 524288);    // 16x2048           128 KB
  float* hbuf     = (float*)(wsb + 655360);    // 16x2048           128 KB
  float* y0       = (float*)(wsb + 786432);    // 16x2048           128 KB
  float* act      = (float*)(wsb + 917504);    // 16x8192           512 KB
  float* scores   = (float*)(wsb + 1441792);   // 16x16x2048          2 MB
  float* pml      = (float*)(wsb + 3538944);   // 16x16               4 KB
  float* pacc     = (float*)(wsb + 3543040);   // 64x16x16x128        8 MB
  float* part     = (float*)(wsb + 11931648);  // up to 8*6144*16     3 MB

  // 1. LN0
  ln_kernel<<<16, 256, 0, stream>>>(input, ln0_w, ln0_b, x_ln);
  // 2. QKV projection (R=6144, K=2048, split 8)
  gemv_k<<<dim3(96, 8), 256, 0, stream>>>(wqkv, x_ln, part, QKV_R, D_, 256);
  reduce_plain<<<384, 256, 0, stream>>>(part, qkv, QKV_R, 8);
  // 3. attention: scores -> softmax -> A@V -> combine
  attn_scores<<<dim3(B_, NSPLIT), 256, 0, stream>>>(qkv, pk, scores);
  attn_soft<<<256, 256, 0, stream>>>(qkv, scores, pml);
  attn_av<<<dim3(B_, NSPLIT), 256, 0, stream>>>(scores, pv, pacc);
  attn_comb<<<256, 128, 0, stream>>>(qkv, pml, pacc, attn_out);
  // 4. output projection + residual (R=2048, K=2048, split 16)
  gemv_k<<<dim3(32, 16), 256, 0, stream>>>(wo, attn_out, part, D_, D_, 128);
  reduce_resid<<<128, 256, 0, stream>>>(part, input, hbuf, D_, 16);
  // 5. LN1
  ln_kernel<<<16, 256, 0, stream>>>(hbuf, ln1_w, ln1_b, y0);
  // 6. FC0 + gelu (R=8192, K=2048, split 4)
  gemv_k<<<dim3(128, 4), 256, 0, stream>>>(fc0_w, y0, part, M_, D_, 512);
  reduce_bias_gelu<<<512, 256, 0, stream>>>(part, fc0_b, act, M_, 4);
  // 7. FC1 + bias + residual (R=2048, K=8192, split 16)
  gemv_k<<<dim3(32, 16), 256, 0, stream>>>(fc1_w, act, part, D_, M_, 512);
  reduce_bias_resid<<<128, 256, 0, stream>>>(part, fc1_b, hbuf, out, D_, 16);
}

// Round 5
// 197.448 us; speedup vs baseline: 1.0693x; 1.0693x over previous
//
#include <hip/hip_runtime.h>
#include <math.h>

typedef __attribute__((ext_vector_type(4))) float f32x4;
typedef __attribute__((ext_vector_type(4))) _Float16 f16x4;

#define B_  16
#define D_  2048
#define H_  16
#define HD_ 128
#define LP_ 2048
#define M_  8192
#define QKV_R (3 * D_)
#define SCALE 0.08838834764831845f   // 1/sqrt(128)
#define NSPLIT 32
#define KPS 64    // keys per split
#define TROWS 2   // key rows per LDS tile (16 KB)
#define NT (KPS / TROWS)

__device__ inline float wave_sum(float v) {
  for (int m = 32; m > 0; m >>= 1) v += __shfl_xor(v, m);
  return v;
}

__device__ inline void gl_lds16(const float* g, float* l) {
  __builtin_amdgcn_global_load_lds(
      (const __attribute__((address_space(1))) void*)g,
      (__attribute__((address_space(3))) void*)l, 16, 0, 0);
}

// ---------------- LayerNorm: one block per batch row, 256 threads ----------
__global__ void ln_kernel(const float* __restrict__ x, const float* __restrict__ w,
                          const float* __restrict__ bb, float* __restrict__ o) {
  __shared__ float sred[4];
  int b = blockIdx.x, t = threadIdx.x;
  const float* xr = x + (size_t)b * D_;
  f32x4 v0 = *(const f32x4*)(xr + t * 8);
  f32x4 v1 = *(const f32x4*)(xr + t * 8 + 4);
  float s = (v0[0] + v0[1] + v0[2] + v0[3]) + (v1[0] + v1[1] + v1[2] + v1[3]);
  s = wave_sum(s);
  if ((t & 63) == 0) sred[t >> 6] = s;
  __syncthreads();
  float mu = (sred[0] + sred[1] + sred[2] + sred[3]) * (1.0f / D_);
  __syncthreads();
  float sq = 0.f;
  for (int i = 0; i < 4; i++) {
    float d0 = v0[i] - mu; sq += d0 * d0;
    float d1 = v1[i] - mu; sq += d1 * d1;
  }
  sq = wave_sum(sq);
  if ((t & 63) == 0) sred[t >> 6] = sq;
  __syncthreads();
  float var = (sred[0] + sred[1] + sred[2] + sred[3]) * (1.0f / D_);
  float rs = rsqrtf(var + 1e-5f);
  f32x4 w0 = *(const f32x4*)(w + t * 8), w1 = *(const f32x4*)(w + t * 8 + 4);
  f32x4 c0 = *(const f32x4*)(bb + t * 8), c1 = *(const f32x4*)(bb + t * 8 + 4);
  f32x4 o0, o1;
  for (int i = 0; i < 4; i++) {
    o0[i] = (v0[i] - mu) * rs * w0[i] + c0[i];
    o1[i] = (v1[i] - mu) * rs * w1[i] + c1[i];
  }
  *(f32x4*)(o + (size_t)b * D_ + t * 8) = o0;
  *(f32x4*)(o + (size_t)b * D_ + t * 8 + 4) = o1;
}

// ---------------- Skinny GEMM: C[16,R] = X[16,K] @ W[R,K]^T ----------------
__global__ void gemv_k(const float* __restrict__ W, const float* __restrict__ X,
                       float* __restrict__ part, int R, int K, int kc) {
  int wave = threadIdx.x >> 6, lane = threadIdx.x & 63;
  int j0 = (blockIdx.x * 4 + wave) * 16;
  int k0 = blockIdx.y * kc;
  int col = lane & 15;
  int kg  = (lane >> 4) << 2;
  const float* wp = W + (size_t)(j0 + col) * K + k0 + kg;
  const float* xp = X + (size_t)col * K + k0 + kg;
  f32x4 acc = {0.f, 0.f, 0.f, 0.f};
  #pragma unroll 4
  for (int kk = 0; kk < kc; kk += 16) {
    f32x4 av = *(const f32x4*)xp; xp += 16;
    f32x4 bv = *(const f32x4*)wp; wp += 16;
    f16x4 ah, bh;
    for (int i = 0; i < 4; i++) { ah[i] = (_Float16)av[i]; bh[i] = (_Float16)bv[i]; }
    acc = __builtin_amdgcn_mfma_f32_16x16x16f16(ah, bh, acc, 0, 0, 0);
  }
  *(f32x4*)(part + ((size_t)blockIdx.y * R + j0 + col) * 16 + kg) = acc;
}

// ---------------- split-K reduce + epilogues -------------------------------
__global__ void reduce_plain(const float* __restrict__ part, float* __restrict__ out,
                             int R, int S) {
  int i = blockIdx.x * 256 + threadIdx.x;
  int j = i >> 4, b = i & 15;
  float s = 0.f;
  for (int k = 0; k < S; k++) s += part[(size_t)k * R * 16 + i];
  out[(size_t)b * R + j] = s;
}
__global__ void reduce_resid(const float* __restrict__ part, const float* __restrict__ resid,
                             float* __restrict__ out, int R, int S) {
  int i = blockIdx.x * 256 + threadIdx.x;
  int j = i >> 4, b = i & 15;
  float s = 0.f;
  for (int k = 0; k < S; k++) s += part[(size_t)k * R * 16 + i];
  out[(size_t)b * R + j] = resid[(size_t)b * R + j] + s;
}
__global__ void reduce_bias_gelu(const float* __restrict__ part, const float* __restrict__ bias,
                                 float* __restrict__ out, int R, int S) {
  int i = blockIdx.x * 256 + threadIdx.x;
  int j = i >> 4, b = i & 15;
  float s = 0.f;
  for (int k = 0; k < S; k++) s += part[(size_t)k * R * 16 + i];
  float u = s + bias[j];
  out[(size_t)b * R + j] = 0.5f * u * (1.0f + erff(u * 0.70710678118654752f));
}
__global__ void reduce_bias_resid(const float* __restrict__ part, const float* __restrict__ bias,
                                  const float* __restrict__ resid, float* __restrict__ out,
                                  int R, int S) {
  int i = blockIdx.x * 256 + threadIdx.x;
  int j = i >> 4, b = i & 15;
  float s = 0.f;
  for (int k = 0; k < S; k++) s += part[(size_t)k * R * 16 + i];
  out[(size_t)b * R + j] = resid[(size_t)b * R + j] + s + bias[j];
}

// ---------------- attention pass 1: scores via LDS-staged K stream ---------
// grid (B, NSPLIT), 256 threads. Double-buffered global_load_lds pipeline:
// stage(t+1) -> s_waitcnt vmcnt(4) -> s_barrier -> consume(t) -> s_barrier.
// Counted vmcnt keeps the next tile's 16 KB in flight across barriers.
__global__ void attn_scores(const float* __restrict__ qkv, const float* __restrict__ pk,
                            float* __restrict__ scores) {
  int b = blockIdx.x, sp = blockIdx.y;
  int t = threadIdx.x;
  int wv = __builtin_amdgcn_readfirstlane(threadIdx.x) >> 6;   // wave id (SGPR)
  int lane = t & 63;
  int h = t >> 4, d8 = (t & 15) * 8;
  __shared__ float kbuf[2][TROWS][D_];
  __shared__ float s_t[H_][KPS + 1];

  f32x4 q0 = *(const f32x4*)(qkv + (size_t)b * QKV_R + h * HD_ + d8);
  f32x4 q1 = *(const f32x4*)(qkv + (size_t)b * QKV_R + h * HD_ + d8 + 4);
  for (int i = 0; i < 4; i++) { q0[i] *= SCALE; q1[i] *= SCALE; }

  const float* gbase = pk + ((size_t)b * LP_ + (size_t)sp * KPS) * D_;
  auto stage = [&](int buf, int tile) {
    const float* src = gbase + (size_t)tile * (TROWS * D_) + wv * 1024 + lane * 4;
    float* dst = &kbuf[buf][0][0] + wv * 1024;
    #pragma unroll
    for (int j = 0; j < 4; j++) gl_lds16(src + j * 256, dst + j * 256);
  };

  stage(0, 0);
  for (int tile = 0; tile < NT; ++tile) {
    int cur = tile & 1;
    if (tile + 1 < NT) {
      stage(cur ^ 1, tile + 1);
      __builtin_amdgcn_sched_barrier(0);
      asm volatile("s_waitcnt vmcnt(4)" ::: "memory");
    } else {
      __builtin_amdgcn_sched_barrier(0);
      asm volatile("s_waitcnt vmcnt(0)" ::: "memory");
    }
    __builtin_amdgcn_s_barrier();
    __builtin_amdgcn_sched_barrier(0);
    #pragma unroll
    for (int r = 0; r < TROWS; ++r) {
      const float* kr = &kbuf[cur][r][h * HD_ + d8];
      f32x4 k0 = *(const f32x4*)kr;
      f32x4 k1 = *(const f32x4*)(kr + 4);
      float s = q0[0]*k0[0] + q0[1]*k0[1] + q0[2]*k0[2] + q0[3]*k0[3]
              + q1[0]*k1[0] + q1[1]*k1[1] + q1[2]*k1[2] + q1[3]*k1[3];
      s += __shfl_xor(s, 1); s += __shfl_xor(s, 2);
      s += __shfl_xor(s, 4); s += __shfl_xor(s, 8);
      if ((t & 15) == 0) s_t[h][tile * TROWS + r] = s;
    }
    asm volatile("" ::: "memory");
    __builtin_amdgcn_s_barrier();
  }
  __syncthreads();
  {
    int l4 = (t & 15) * 4;
    f32x4 o;
    for (int i = 0; i < 4; i++) o[i] = s_t[h][l4 + i];
    *(f32x4*)(scores + (size_t)(b * H_ + h) * LP_ + (size_t)sp * KPS + l4) = o;
  }
}

// ---------------- attention pass 2: softmax over 2048+1 -------------------
__global__ void attn_soft(const float* __restrict__ qkv, float* __restrict__ scores,
                          float* __restrict__ pml) {
  int bh = blockIdx.x, b = bh >> 4, h = bh & 15;
  int t = threadIdx.x;
  __shared__ float sred[4];
  float prod = 0.f;
  if (t < 128) {
    float qv = qkv[(size_t)b * QKV_R + h * HD_ + t];
    float kn = qkv[(size_t)b * QKV_R + D_ + h * HD_ + t];
    prod = qv * kn;
  }
  prod = wave_sum(prod);
  if ((t & 63) == 0) sred[t >> 6] = prod;
  __syncthreads();
  float s_new = (sred[0] + sred[1] + sred[2] + sred[3]) * SCALE;
  __syncthreads();
  float* sp = scores + (size_t)bh * LP_;
  f32x4 v0 = *(const f32x4*)(sp + t * 8);
  f32x4 v1 = *(const f32x4*)(sp + t * 8 + 4);
  float m = s_new;
  for (int i = 0; i < 4; i++) m = fmaxf(m, fmaxf(v0[i], v1[i]));
  for (int mm = 32; mm > 0; mm >>= 1) m = fmaxf(m, __shfl_xor(m, mm));
  if ((t & 63) == 0) sred[t >> 6] = m;
  __syncthreads();
  float M = fmaxf(fmaxf(sred[0], sred[1]), fmaxf(sred[2], sred[3]));
  __syncthreads();
  float ls = 0.f;
  for (int i = 0; i < 4; i++) {
    v0[i] = __expf(v0[i] - M); ls += v0[i];
    v1[i] = __expf(v1[i] - M); ls += v1[i];
  }
  ls = wave_sum(ls);
  if ((t & 63) == 0) sred[t >> 6] = ls;
  __syncthreads();
  float en = __expf(s_new - M);
  float L = sred[0] + sred[1] + sred[2] + sred[3] + en;
  float inv = 1.0f / L;
  for (int i = 0; i < 4; i++) { v0[i] *= inv; v1[i] *= inv; }
  *(f32x4*)(sp + t * 8) = v0;
  *(f32x4*)(sp + t * 8 + 4) = v1;
  if (t == 0) pml[bh] = en * inv;
}

// ---------------- attention pass 3: A@V via LDS-staged V stream ------------
__global__ void attn_av(const float* __restrict__ scores, const float* __restrict__ pv,
                        float* __restrict__ pacc) {
  int b = blockIdx.x, sp = blockIdx.y;
  int t = threadIdx.x;
  int wv = __builtin_amdgcn_readfirstlane(threadIdx.x) >> 6;
  int lane = t & 63;
  int h = t >> 4, d8 = (t & 15) * 8;
  __shared__ float vbuf[2][TROWS][D_];
  __shared__ float p_l[H_][KPS + 1];

  {  // stage normalized probs for this block's keys into LDS
    int l4 = (t & 15) * 4;
    f32x4 pr = *(const f32x4*)(scores + (size_t)(b * H_ + h) * LP_ + (size_t)sp * KPS + l4);
    for (int i = 0; i < 4; i++) p_l[h][l4 + i] = pr[i];
  }

  const float* gbase = pv + ((size_t)b * LP_ + (size_t)sp * KPS) * D_;
  auto stage = [&](int buf, int tile) {
    const float* src = gbase + (size_t)tile * (TROWS * D_) + wv * 1024 + lane * 4;
    float* dst = &vbuf[buf][0][0] + wv * 1024;
    #pragma unroll
    for (int j = 0; j < 4; j++) gl_lds16(src + j * 256, dst + j * 256);
  };

  stage(0, 0);
  __syncthreads();   // p_l visible (also drains tile-0 stage; prologue only)

  f32x4 a0 = {0.f, 0.f, 0.f, 0.f}, a1 = {0.f, 0.f, 0.f, 0.f};
  for (int tile = 0; tile < NT; ++tile) {
    int cur = tile & 1;
    if (tile + 1 < NT) {
      stage(cur ^ 1, tile + 1);
      __builtin_amdgcn_sched_barrier(0);
      asm volatile("s_waitcnt vmcnt(4)" ::: "memory");
    } else {
      __builtin_amdgcn_sched_barrier(0);
      asm volatile("s_waitcnt vmcnt(0)" ::: "memory");
    }
    __builtin_amdgcn_s_barrier();
    __builtin_amdgcn_sched_barrier(0);
    #pragma unroll
    for (int r = 0; r < TROWS; ++r) {
      float p = p_l[h][tile * TROWS + r];
      const float* vr = &vbuf[cur][r][h * HD_ + d8];
      f32x4 v0 = *(const f32x4*)vr;
      f32x4 v1 = *(const f32x4*)(vr + 4);
      for (int i = 0; i < 4; i++) { a0[i] += p * v0[i]; a1[i] += p * v1[i]; }
    }
    asm volatile("" ::: "memory");
    __builtin_amdgcn_s_barrier();
  }
  size_t oi = (((size_t)b * NSPLIT + sp) * H_ + h) * HD_ + d8;
  *(f32x4*)(pacc + oi) = a0;
  *(f32x4*)(pacc + oi + 4) = a1;
}

// ---------------- combine partials + new token -----------------------------
__global__ void attn_comb(const float* __restrict__ qkv, const float* __restrict__ pml,
                          const float* __restrict__ pacc, float* __restrict__ attn_out) {
  int bh = blockIdx.x, b = bh >> 4, h = bh & 15;
  int t = threadIdx.x;  // 128
  float o = 0.f;
  for (int s = 0; s < NSPLIT; s++)
    o += pacc[(((size_t)b * NSPLIT + s) * H_ + h) * HD_ + t];
  o += pml[bh] * qkv[(size_t)b * QKV_R + 2 * D_ + h * HD_ + t];
  attn_out[(size_t)b * D_ + h * HD_ + t] = o;
}

extern "C" void kernel_launch(void* const* d_in, const int* in_sizes, int n_in,
                              void* d_out, int out_size, void* d_ws, size_t ws_size,
                              hipStream_t stream) {
  const float* input  = (const float*)d_in[0];
  const float* pk     = (const float*)d_in[1];
  const float* pv     = (const float*)d_in[2];
  const float* ln0_w  = (const float*)d_in[3];
  const float* ln0_b  = (const float*)d_in[4];
  const float* ln1_w  = (const float*)d_in[5];
  const float* ln1_b  = (const float*)d_in[6];
  const float* wqkv   = (const float*)d_in[7];
  const float* wo     = (const float*)d_in[8];
  const float* fc0_w  = (const float*)d_in[9];
  const float* fc0_b  = (const float*)d_in[10];
  const float* fc1_w  = (const float*)d_in[11];
  const float* fc1_b  = (const float*)d_in[12];
  float* out = (float*)d_out;

  char* wsb = (char*)d_ws;
  float* x_ln     = (float*)(wsb + 0);         // 16x2048           128 KB
  float* qkv      = (float*)(wsb + 131072);    // 16x6144           384 KB
  float* attn_out = (float*)(wsb + 524288);    // 16x2048           128 KB
  float* hbuf     = (float*)(wsb + 655360);    // 16x2048           128 KB
  float* y0       = (float*)(wsb + 786432);    // 16x2048           128 KB
  float* act      = (float*)(wsb + 917504);    // 16x8192           512 KB
  float* scores   = (float*)(wsb + 1441792);   // 16x16x2048          2 MB
  float* pml      = (float*)(wsb + 3538944);   // 16x16               4 KB
  float* pacc     = (float*)(wsb + 3543040);   // 32x16x16x128        4 MB
  float* part     = (float*)(wsb + 11931648);  // up to 8*6144*16     3 MB

  // 1. LN0
  ln_kernel<<<16, 256, 0, stream>>>(input, ln0_w, ln0_b, x_ln);
  // 2. QKV projection (R=6144, K=2048, split 8)
  gemv_k<<<dim3(96, 8), 256, 0, stream>>>(wqkv, x_ln, part, QKV_R, D_, 256);
  reduce_plain<<<384, 256, 0, stream>>>(part, qkv, QKV_R, 8);
  // 3. attention: scores -> softmax -> A@V -> combine
  attn_scores<<<dim3(B_, NSPLIT), 256, 0, stream>>>(qkv, pk, scores);
  attn_soft<<<256, 256, 0, stream>>>(qkv, scores, pml);
  attn_av<<<dim3(B_, NSPLIT), 256, 0, stream>>>(scores, pv, pacc);
  attn_comb<<<256, 128, 0, stream>>>(qkv, pml, pacc, attn_out);
  // 4. output projection + residual (R=2048, K=2048, split 16)
  gemv_k<<<dim3(32, 16), 256, 0, stream>>>(wo, attn_out, part, D_, D_, 128);
  reduce_resid<<<128, 256, 0, stream>>>(part, input, hbuf, D_, 16);
  // 5. LN1
  ln_kernel<<<16, 256, 0, stream>>>(hbuf, ln1_w, ln1_b, y0);
  // 6. FC0 + gelu (R=8192, K=2048, split 4)
  gemv_k<<<dim3(128, 4), 256, 0, stream>>>(fc0_w, y0, part, M_, D_, 512);
  reduce_bias_gelu<<<512, 256, 0, stream>>>(part, fc0_b, act, M_, 4);
  // 7. FC1 + bias + residual (R=2048, K=8192, split 16)
  gemv_k<<<dim3(32, 16), 256, 0, stream>>>(fc1_w, act, part, D_, M_, 512);
  reduce_bias_resid<<<128, 256, 0, stream>>>(part, fc1_b, hbuf, out, D_, 16);
}

// Round 6
// 193.822 us; speedup vs baseline: 1.0893x; 1.0187x over previous
//
#include <hip/hip_runtime.h>
#include <math.h>

typedef __attribute__((ext_vector_type(4))) float f32x4;
typedef __attribute__((ext_vector_type(4))) _Float16 f16x4;

#define B_  16
#define D_  2048
#define H_  16
#define HD_ 128
#define LP_ 2048
#define M_  8192
#define QKV_R (3 * D_)
#define SCALE 0.08838834764831845f   // 1/sqrt(128)
#define NSPLIT 32
#define KPS 64    // keys per split
#define TROWS 4   // key rows per LDS tile (32 KB)
#define NT (KPS / TROWS)

__device__ inline float wave_sum(float v) {
  for (int m = 32; m > 0; m >>= 1) v += __shfl_xor(v, m);
  return v;
}

// global->LDS direct, 16B/lane, NT cache policy (single-use stream: don't
// thrash L3; aux bit1 = NT on gfx94x/950 cpol encoding)
__device__ inline void gl_lds16(const float* g, float* l) {
  __builtin_amdgcn_global_load_lds(
      (const __attribute__((address_space(1))) void*)g,
      (__attribute__((address_space(3))) void*)l, 16, 0, 2 /*NT*/);
}

// ---------------- LayerNorm: one block per batch row, 256 threads ----------
__global__ void ln_kernel(const float* __restrict__ x, const float* __restrict__ w,
                          const float* __restrict__ bb, float* __restrict__ o) {
  __shared__ float sred[4];
  int b = blockIdx.x, t = threadIdx.x;
  const float* xr = x + (size_t)b * D_;
  f32x4 v0 = *(const f32x4*)(xr + t * 8);
  f32x4 v1 = *(const f32x4*)(xr + t * 8 + 4);
  float s = (v0[0] + v0[1] + v0[2] + v0[3]) + (v1[0] + v1[1] + v1[2] + v1[3]);
  s = wave_sum(s);
  if ((t & 63) == 0) sred[t >> 6] = s;
  __syncthreads();
  float mu = (sred[0] + sred[1] + sred[2] + sred[3]) * (1.0f / D_);
  __syncthreads();
  float sq = 0.f;
  for (int i = 0; i < 4; i++) {
    float d0 = v0[i] - mu; sq += d0 * d0;
    float d1 = v1[i] - mu; sq += d1 * d1;
  }
  sq = wave_sum(sq);
  if ((t & 63) == 0) sred[t >> 6] = sq;
  __syncthreads();
  float var = (sred[0] + sred[1] + sred[2] + sred[3]) * (1.0f / D_);
  float rs = rsqrtf(var + 1e-5f);
  f32x4 w0 = *(const f32x4*)(w + t * 8), w1 = *(const f32x4*)(w + t * 8 + 4);
  f32x4 c0 = *(const f32x4*)(bb + t * 8), c1 = *(const f32x4*)(bb + t * 8 + 4);
  f32x4 o0, o1;
  for (int i = 0; i < 4; i++) {
    o0[i] = (v0[i] - mu) * rs * w0[i] + c0[i];
    o1[i] = (v1[i] - mu) * rs * w1[i] + c1[i];
  }
  *(f32x4*)(o + (size_t)b * D_ + t * 8) = o0;
  *(f32x4*)(o + (size_t)b * D_ + t * 8 + 4) = o1;
}

// ---------------- Skinny GEMM: C[16,R] = X[16,K] @ W[R,K]^T ----------------
// W rows are single-use -> nontemporal; X is reused across blocks -> cached.
__global__ void gemv_k(const float* __restrict__ W, const float* __restrict__ X,
                       float* __restrict__ part, int R, int K, int kc) {
  int wave = threadIdx.x >> 6, lane = threadIdx.x & 63;
  int j0 = (blockIdx.x * 4 + wave) * 16;
  int k0 = blockIdx.y * kc;
  int col = lane & 15;
  int kg  = (lane >> 4) << 2;
  const float* wp = W + (size_t)(j0 + col) * K + k0 + kg;
  const float* xp = X + (size_t)col * K + k0 + kg;
  f32x4 acc = {0.f, 0.f, 0.f, 0.f};
  #pragma unroll 4
  for (int kk = 0; kk < kc; kk += 16) {
    f32x4 av = *(const f32x4*)xp; xp += 16;
    f32x4 bv = __builtin_nontemporal_load((const f32x4*)wp); wp += 16;
    f16x4 ah, bh;
    for (int i = 0; i < 4; i++) { ah[i] = (_Float16)av[i]; bh[i] = (_Float16)bv[i]; }
    acc = __builtin_amdgcn_mfma_f32_16x16x16f16(ah, bh, acc, 0, 0, 0);
  }
  *(f32x4*)(part + ((size_t)blockIdx.y * R + j0 + col) * 16 + kg) = acc;
}

// ---------------- split-K reduce + epilogues -------------------------------
__global__ void reduce_plain(const float* __restrict__ part, float* __restrict__ out,
                             int R, int S) {
  int i = blockIdx.x * 256 + threadIdx.x;
  int j = i >> 4, b = i & 15;
  float s = 0.f;
  for (int k = 0; k < S; k++) s += part[(size_t)k * R * 16 + i];
  out[(size_t)b * R + j] = s;
}
__global__ void reduce_resid(const float* __restrict__ part, const float* __restrict__ resid,
                             float* __restrict__ out, int R, int S) {
  int i = blockIdx.x * 256 + threadIdx.x;
  int j = i >> 4, b = i & 15;
  float s = 0.f;
  for (int k = 0; k < S; k++) s += part[(size_t)k * R * 16 + i];
  out[(size_t)b * R + j] = resid[(size_t)b * R + j] + s;
}
__global__ void reduce_bias_gelu(const float* __restrict__ part, const float* __restrict__ bias,
                                 float* __restrict__ out, int R, int S) {
  int i = blockIdx.x * 256 + threadIdx.x;
  int j = i >> 4, b = i & 15;
  float s = 0.f;
  for (int k = 0; k < S; k++) s += part[(size_t)k * R * 16 + i];
  float u = s + bias[j];
  out[(size_t)b * R + j] = 0.5f * u * (1.0f + erff(u * 0.70710678118654752f));
}
__global__ void reduce_bias_resid(const float* __restrict__ part, const float* __restrict__ bias,
                                  const float* __restrict__ resid, float* __restrict__ out,
                                  int R, int S) {
  int i = blockIdx.x * 256 + threadIdx.x;
  int j = i >> 4, b = i & 15;
  float s = 0.f;
  for (int k = 0; k < S; k++) s += part[(size_t)k * R * 16 + i];
  out[(size_t)b * R + j] = resid[(size_t)b * R + j] + s + bias[j];
}

// ---------------- attention pass 1: scores via LDS-staged K stream ---------
// grid (B, NSPLIT), 256 threads. Double-buffered global_load_lds pipeline,
// 32 KB tiles, counted vmcnt(8) -> 32 KB/block (64 KB/CU) always in flight.
__global__ void attn_scores(const float* __restrict__ qkv, const float* __restrict__ pk,
                            float* __restrict__ scores) {
  int b = blockIdx.x, sp = blockIdx.y;
  int t = threadIdx.x;
  int wv = __builtin_amdgcn_readfirstlane(threadIdx.x) >> 6;   // wave id (SGPR)
  int lane = t & 63;
  int h = t >> 4, d8 = (t & 15) * 8;
  __shared__ float kbuf[2][TROWS][D_];
  __shared__ float s_t[H_][KPS + 1];

  f32x4 q0 = *(const f32x4*)(qkv + (size_t)b * QKV_R + h * HD_ + d8);
  f32x4 q1 = *(const f32x4*)(qkv + (size_t)b * QKV_R + h * HD_ + d8 + 4);
  for (int i = 0; i < 4; i++) { q0[i] *= SCALE; q1[i] *= SCALE; }

  const float* gbase = pk + ((size_t)b * LP_ + (size_t)sp * KPS) * D_;
  auto stage = [&](int buf, int tile) {
    // wave wv covers bytes [wv*8KB, (wv+1)*8KB) of the 32KB tile
    const float* src = gbase + (size_t)tile * (TROWS * D_) + wv * 2048 + lane * 4;
    float* dst = &kbuf[buf][0][0] + wv * 2048;
    #pragma unroll
    for (int j = 0; j < 8; j++) gl_lds16(src + j * 256, dst + j * 256);
  };

  stage(0, 0);
  for (int tile = 0; tile < NT; ++tile) {
    int cur = tile & 1;
    if (tile + 1 < NT) {
      stage(cur ^ 1, tile + 1);
      __builtin_amdgcn_sched_barrier(0);
      asm volatile("s_waitcnt vmcnt(8)" ::: "memory");
    } else {
      __builtin_amdgcn_sched_barrier(0);
      asm volatile("s_waitcnt vmcnt(0)" ::: "memory");
    }
    __builtin_amdgcn_s_barrier();
    __builtin_amdgcn_sched_barrier(0);
    #pragma unroll
    for (int r = 0; r < TROWS; ++r) {
      const float* kr = &kbuf[cur][r][h * HD_ + d8];
      f32x4 k0 = *(const f32x4*)kr;
      f32x4 k1 = *(const f32x4*)(kr + 4);
      float s = q0[0]*k0[0] + q0[1]*k0[1] + q0[2]*k0[2] + q0[3]*k0[3]
              + q1[0]*k1[0] + q1[1]*k1[1] + q1[2]*k1[2] + q1[3]*k1[3];
      s += __shfl_xor(s, 1); s += __shfl_xor(s, 2);
      s += __shfl_xor(s, 4); s += __shfl_xor(s, 8);
      if ((t & 15) == 0) s_t[h][tile * TROWS + r] = s;
    }
    asm volatile("" ::: "memory");
    __builtin_amdgcn_s_barrier();
  }
  __syncthreads();
  {
    int l4 = (t & 15) * 4;
    f32x4 o;
    for (int i = 0; i < 4; i++) o[i] = s_t[h][l4 + i];
    *(f32x4*)(scores + (size_t)(b * H_ + h) * LP_ + (size_t)sp * KPS + l4) = o;
  }
}

// ---------------- attention pass 2: softmax over 2048+1 -------------------
__global__ void attn_soft(const float* __restrict__ qkv, float* __restrict__ scores,
                          float* __restrict__ pml) {
  int bh = blockIdx.x, b = bh >> 4, h = bh & 15;
  int t = threadIdx.x;
  __shared__ float sred[4];
  float prod = 0.f;
  if (t < 128) {
    float qv = qkv[(size_t)b * QKV_R + h * HD_ + t];
    float kn = qkv[(size_t)b * QKV_R + D_ + h * HD_ + t];
    prod = qv * kn;
  }
  prod = wave_sum(prod);
  if ((t & 63) == 0) sred[t >> 6] = prod;
  __syncthreads();
  float s_new = (sred[0] + sred[1] + sred[2] + sred[3]) * SCALE;
  __syncthreads();
  float* sp = scores + (size_t)bh * LP_;
  f32x4 v0 = *(const f32x4*)(sp + t * 8);
  f32x4 v1 = *(const f32x4*)(sp + t * 8 + 4);
  float m = s_new;
  for (int i = 0; i < 4; i++) m = fmaxf(m, fmaxf(v0[i], v1[i]));
  for (int mm = 32; mm > 0; mm >>= 1) m = fmaxf(m, __shfl_xor(m, mm));
  if ((t & 63) == 0) sred[t >> 6] = m;
  __syncthreads();
  float M = fmaxf(fmaxf(sred[0], sred[1]), fmaxf(sred[2], sred[3]));
  __syncthreads();
  float ls = 0.f;
  for (int i = 0; i < 4; i++) {
    v0[i] = __expf(v0[i] - M); ls += v0[i];
    v1[i] = __expf(v1[i] - M); ls += v1[i];
  }
  ls = wave_sum(ls);
  if ((t & 63) == 0) sred[t >> 6] = ls;
  __syncthreads();
  float en = __expf(s_new - M);
  float L = sred[0] + sred[1] + sred[2] + sred[3] + en;
  float inv = 1.0f / L;
  for (int i = 0; i < 4; i++) { v0[i] *= inv; v1[i] *= inv; }
  *(f32x4*)(sp + t * 8) = v0;
  *(f32x4*)(sp + t * 8 + 4) = v1;
  if (t == 0) pml[bh] = en * inv;
}

// ---------------- attention pass 3: A@V via LDS-staged V stream ------------
__global__ void attn_av(const float* __restrict__ scores, const float* __restrict__ pv,
                        float* __restrict__ pacc) {
  int b = blockIdx.x, sp = blockIdx.y;
  int t = threadIdx.x;
  int wv = __builtin_amdgcn_readfirstlane(threadIdx.x) >> 6;
  int lane = t & 63;
  int h = t >> 4, d8 = (t & 15) * 8;
  __shared__ float vbuf[2][TROWS][D_];
  __shared__ float p_l[H_][KPS + 1];

  {  // stage normalized probs for this block's keys into LDS
    int l4 = (t & 15) * 4;
    f32x4 pr = *(const f32x4*)(scores + (size_t)(b * H_ + h) * LP_ + (size_t)sp * KPS + l4);
    for (int i = 0; i < 4; i++) p_l[h][l4 + i] = pr[i];
  }

  const float* gbase = pv + ((size_t)b * LP_ + (size_t)sp * KPS) * D_;
  auto stage = [&](int buf, int tile) {
    const float* src = gbase + (size_t)tile * (TROWS * D_) + wv * 2048 + lane * 4;
    float* dst = &vbuf[buf][0][0] + wv * 2048;
    #pragma unroll
    for (int j = 0; j < 8; j++) gl_lds16(src + j * 256, dst + j * 256);
  };

  stage(0, 0);
  __syncthreads();   // p_l visible (also drains tile-0 stage; prologue only)

  f32x4 a0 = {0.f, 0.f, 0.f, 0.f}, a1 = {0.f, 0.f, 0.f, 0.f};
  for (int tile = 0; tile < NT; ++tile) {
    int cur = tile & 1;
    if (tile + 1 < NT) {
      stage(cur ^ 1, tile + 1);
      __builtin_amdgcn_sched_barrier(0);
      asm volatile("s_waitcnt vmcnt(8)" ::: "memory");
    } else {
      __builtin_amdgcn_sched_barrier(0);
      asm volatile("s_waitcnt vmcnt(0)" ::: "memory");
    }
    __builtin_amdgcn_s_barrier();
    __builtin_amdgcn_sched_barrier(0);
    #pragma unroll
    for (int r = 0; r < TROWS; ++r) {
      float p = p_l[h][tile * TROWS + r];
      const float* vr = &vbuf[cur][r][h * HD_ + d8];
      f32x4 v0 = *(const f32x4*)vr;
      f32x4 v1 = *(const f32x4*)(vr + 4);
      for (int i = 0; i < 4; i++) { a0[i] += p * v0[i]; a1[i] += p * v1[i]; }
    }
    asm volatile("" ::: "memory");
    __builtin_amdgcn_s_barrier();
  }
  size_t oi = (((size_t)b * NSPLIT + sp) * H_ + h) * HD_ + d8;
  *(f32x4*)(pacc + oi) = a0;
  *(f32x4*)(pacc + oi + 4) = a1;
}

// ---------------- combine partials + new token -----------------------------
__global__ void attn_comb(const float* __restrict__ qkv, const float* __restrict__ pml,
                          const float* __restrict__ pacc, float* __restrict__ attn_out) {
  int bh = blockIdx.x, b = bh >> 4, h = bh & 15;
  int t = threadIdx.x;  // 128
  float o = 0.f;
  for (int s = 0; s < NSPLIT; s++)
    o += pacc[(((size_t)b * NSPLIT + s) * H_ + h) * HD_ + t];
  o += pml[bh] * qkv[(size_t)b * QKV_R + 2 * D_ + h * HD_ + t];
  attn_out[(size_t)b * D_ + h * HD_ + t] = o;
}

extern "C" void kernel_launch(void* const* d_in, const int* in_sizes, int n_in,
                              void* d_out, int out_size, void* d_ws, size_t ws_size,
                              hipStream_t stream) {
  const float* input  = (const float*)d_in[0];
  const float* pk     = (const float*)d_in[1];
  const float* pv     = (const float*)d_in[2];
  const float* ln0_w  = (const float*)d_in[3];
  const float* ln0_b  = (const float*)d_in[4];
  const float* ln1_w  = (const float*)d_in[5];
  const float* ln1_b  = (const float*)d_in[6];
  const float* wqkv   = (const float*)d_in[7];
  const float* wo     = (const float*)d_in[8];
  const float* fc0_w  = (const float*)d_in[9];
  const float* fc0_b  = (const float*)d_in[10];
  const float* fc1_w  = (const float*)d_in[11];
  const float* fc1_b  = (const float*)d_in[12];
  float* out = (float*)d_out;

  char* wsb = (char*)d_ws;
  float* x_ln     = (float*)(wsb + 0);         // 16x2048           128 KB
  float* qkv      = (float*)(wsb + 131072);    // 16x6144           384 KB
  float* attn_out = (float*)(wsb + 524288);    // 16x2048           128 KB
  float* hbuf     = (float*)(wsb + 655360);    // 16x2048           128 KB
  float* y0       = (float*)(wsb + 786432);    // 16x2048           128 KB
  float* act      = (float*)(wsb + 917504);    // 16x8192           512 KB
  float* scores   = (float*)(wsb + 1441792);   // 16x16x2048          2 MB
  float* pml      = (float*)(wsb + 3538944);   // 16x16               4 KB
  float* pacc     = (float*)(wsb + 3543040);   // 32x16x16x128        4 MB
  float* part     = (float*)(wsb + 11931648);  // up to 8*6144*16     3 MB

  // 1. LN0
  ln_kernel<<<16, 256, 0, stream>>>(input, ln0_w, ln0_b, x_ln);
  // 2. QKV projection (R=6144, K=2048, split 8)
  gemv_k<<<dim3(96, 8), 256, 0, stream>>>(wqkv, x_ln, part, QKV_R, D_, 256);
  reduce_plain<<<384, 256, 0, stream>>>(part, qkv, QKV_R, 8);
  // 3. attention: scores -> softmax -> A@V -> combine
  attn_scores<<<dim3(B_, NSPLIT), 256, 0, stream>>>(qkv, pk, scores);
  attn_soft<<<256, 256, 0, stream>>>(qkv, scores, pml);
  attn_av<<<dim3(B_, NSPLIT), 256, 0, stream>>>(scores, pv, pacc);
  attn_comb<<<256, 128, 0, stream>>>(qkv, pml, pacc, attn_out);
  // 4. output projection + residual (R=2048, K=2048, split 16)
  gemv_k<<<dim3(32, 16), 256, 0, stream>>>(wo, attn_out, part, D_, D_, 128);
  reduce_resid<<<128, 256, 0, stream>>>(part, input, hbuf, D_, 16);
  // 5. LN1
  ln_kernel<<<16, 256, 0, stream>>>(hbuf, ln1_w, ln1_b, y0);
  // 6. FC0 + gelu (R=8192, K=2048, split 4)
  gemv_k<<<dim3(128, 4), 256, 0, stream>>>(fc0_w, y0, part, M_, D_, 512);
  reduce_bias_gelu<<<512, 256, 0, stream>>>(part, fc0_b, act, M_, 4);
  // 7. FC1 + bias + residual (R=2048, K=8192, split 16)
  gemv_k<<<dim3(32, 16), 256, 0, stream>>>(fc1_w, act, part, D_, M_, 512);
  reduce_bias_resid<<<128, 256, 0, stream>>>(part, fc1_b, hbuf, out, D_, 16);
}